// Round 5
// baseline (522.909 us; speedup 1.0000x reference)
//
#include <hip/hip_runtime.h>

// GCN 2-layer. R6: bf16-MFMA GEMMs (no LDS, operand-swap epilogue). R9:
// atomic-free CSR (two-level bucket sort; device fetch-add ~24 Gops/s wall).
// R10: scalar edge fetch (VALUBusy 60->37% but dur flat => L2-miss bound).
// R11: SLAB-MAJOR features + XCD-pinned slice gathers — h1/agg1/h2 stored as
// 8-dword slabs (slab s = feature cols [8s,8s+8), contiguous n*32B = 3.2MB,
// line-pure). Gather waves take slice = blockIdx&7 so each XCD's L2 holds
// exactly its slab (fits 4MB) -> gather becomes L2-BW-bound, not L3-bound.
// ew read via nontemporal loads (don't evict the pinned slab). GEMM C-write
// and A-read permuted to slab layout (fragment contents bit-identical).
// 4B edge payload src(17b)|ws15. Features bf16-pair packed.

typedef unsigned int u32;
using bfrag = __attribute__((ext_vector_type(8))) short;   // 8 bf16 (4 VGPRs)
using f4    = __attribute__((ext_vector_type(4))) float;   // 4 fp32 acc

__device__ inline u32 pack_bf16(float a, float b) {
    u32 ua = __float_as_uint(a);
    u32 ub = __float_as_uint(b);
    ua += 0x7fffu + ((ua >> 16) & 1u);   // RNE
    ub += 0x7fffu + ((ub >> 16) & 1u);
    return (ua >> 16) | (ub & 0xffff0000u);
}
__device__ inline float bf_lo(u32 v) { return __uint_as_float(v << 16); }
__device__ inline float bf_hi(u32 v) { return __uint_as_float(v & 0xffff0000u); }

// w in [2^-8, 1] -> 15 bits: ws = (bits(w) + rnd - 0x3B800000) >> 12.
__device__ inline u32 pack_w(float w) {
    u32 b = __float_as_uint(w) + 0x800u;       // round mantissa at 11 bits
    if (b < 0x3B800000u) b = 0x3B800000u;      // clamp to 2^-8 (unreachable)
    if (b > 0x3F800000u) b = 0x3F800000u;      // clamp to 1.0
    return (b - 0x3B800000u) >> 12;            // 15 bits
}
__device__ inline float dec_w(u32 e) {
    return __uint_as_float(((e & 0x7fffu) << 12) + 0x3B800000u);
}

__device__ inline int rfl(int v) { return __builtin_amdgcn_readfirstlane(v); }

__device__ inline bfrag as_bfrag(uint4 v) {
    union { uint4 u; bfrag b; } x; x.u = v; return x.b;
}

// ---------------- atomic-free CSR build ----------------

__global__ __launch_bounds__(256) void count_bins(const int* __restrict__ dst,
                                                  int* __restrict__ bc,
                                                  int E, int nbin, int nb3) {
    __shared__ int hist[512];
    for (int t = threadIdx.x; t < nbin; t += 256) hist[t] = 0;
    __syncthreads();
    const int base = blockIdx.x * 2048 + threadIdx.x;
#pragma unroll
    for (int k = 0; k < 8; ++k) {
        int e = base + k * 256;
        if (e < E) atomicAdd(&hist[dst[e] >> 8], 1);
    }
    __syncthreads();
    for (int t = threadIdx.x; t < nbin; t += 256)
        bc[(size_t)t * nb3 + blockIdx.x] = hist[t];
}

__global__ __launch_bounds__(1024) void scan_reduce_g(const int* __restrict__ a,
                                                      int* __restrict__ bsum, int M) {
    __shared__ int wsum[16];
    int i = blockIdx.x * 1024 + threadIdx.x;
    int v = (i < M) ? a[i] : 0;
#pragma unroll
    for (int off = 32; off > 0; off >>= 1) v += __shfl_down(v, off);
    const int lane = threadIdx.x & 63;
    const int wid  = threadIdx.x >> 6;
    if (lane == 0) wsum[wid] = v;
    __syncthreads();
    if (threadIdx.x < 16) {
        int s = wsum[threadIdx.x];
#pragma unroll
        for (int off = 8; off > 0; off >>= 1) s += __shfl_down(s, off);
        if (threadIdx.x == 0) bsum[blockIdx.x] = s;
    }
}

__global__ void scan_partials(const int* __restrict__ bsum, int* __restrict__ boff,
                              int* __restrict__ total_out, int nb) {
    const int lane = threadIdx.x;  // 64 threads
    int carry = 0;
    for (int base = 0; base < nb; base += 64) {
        int i = base + lane;
        int v = (i < nb) ? bsum[i] : 0;
        int x = v;
#pragma unroll
        for (int off = 1; off < 64; off <<= 1) {
            int t = __shfl_up(x, off);
            if (lane >= off) x += t;
        }
        if (i < nb) boff[i] = carry + x - v;
        carry += __shfl(x, 63);
    }
    if (lane == 0) *total_out = carry;
}

__global__ __launch_bounds__(1024) void scan_apply_g(int* __restrict__ a,
                                                     const int* __restrict__ boff, int M) {
    __shared__ int wsum[16];
    const int lane = threadIdx.x & 63;
    const int wid  = threadIdx.x >> 6;
    int i = blockIdx.x * 1024 + threadIdx.x;
    int v = (i < M) ? a[i] : 0;
    int x = v;
#pragma unroll
    for (int off = 1; off < 64; off <<= 1) {
        int t = __shfl_up(x, off);
        if (lane >= off) x += t;
    }
    if (lane == 63) wsum[wid] = x;
    __syncthreads();
    if (wid == 0 && lane < 16) {
        int w = wsum[lane];
#pragma unroll
        for (int off = 1; off < 16; off <<= 1) {
            int t = __shfl_up(w, off);
            if (lane >= off) w += t;
        }
        wsum[lane] = w;
    }
    __syncthreads();
    int wave_excl = (wid == 0) ? 0 : wsum[wid - 1];
    if (i < M) a[i] = boff[blockIdx.x] + wave_excl + (x - v);
}

__global__ __launch_bounds__(1024) void scan_apply_cnt(const int* __restrict__ cnt,
                                                       const int* __restrict__ boff,
                                                       int* __restrict__ row_ptr,
                                                       float* __restrict__ dinv, int n) {
    __shared__ int wsum[16];
    const int lane = threadIdx.x & 63;
    const int wid  = threadIdx.x >> 6;
    int i = blockIdx.x * 1024 + threadIdx.x;
    int v = (i < n) ? cnt[i] : 0;
    int x = v;
#pragma unroll
    for (int off = 1; off < 64; off <<= 1) {
        int t = __shfl_up(x, off);
        if (lane >= off) x += t;
    }
    if (lane == 63) wsum[wid] = x;
    __syncthreads();
    if (wid == 0 && lane < 16) {
        int w = wsum[lane];
#pragma unroll
        for (int off = 1; off < 16; off <<= 1) {
            int t = __shfl_up(w, off);
            if (lane >= off) w += t;
        }
        wsum[lane] = w;
    }
    __syncthreads();
    int wave_excl = (wid == 0) ? 0 : wsum[wid - 1];
    if (i < n) {
        row_ptr[i] = boff[blockIdx.x] + wave_excl + (x - v);
        dinv[i]    = rsqrtf((float)v + 1.0f);
    }
}

__global__ __launch_bounds__(256) void scatter_bins(const int* __restrict__ src,
                                                    const int* __restrict__ dst,
                                                    const int* __restrict__ offs,
                                                    u32* __restrict__ tmp,
                                                    int E, int nbin, int nb3) {
    __shared__ int cur[512];
    for (int t = threadIdx.x; t < nbin; t += 256)
        cur[t] = offs[(size_t)t * nb3 + blockIdx.x];
    __syncthreads();
    const int base = blockIdx.x * 2048 + threadIdx.x;
#pragma unroll
    for (int k = 0; k < 8; ++k) {
        int e = base + k * 256;
        if (e < E) {
            int d = dst[e];
            int pos = atomicAdd(&cur[d >> 8], 1);
            tmp[pos] = ((u32)(d & 255) << 17) | (u32)src[e];
        }
    }
}

__global__ __launch_bounds__(256) void bucket_csr(const u32* __restrict__ tmp,
                                                  const int* __restrict__ offs,
                                                  u32* __restrict__ tmp3,
                                                  int* __restrict__ cnt,
                                                  int n, int nb3) {
    __shared__ int hist[256];
    __shared__ int cur[256];
    __shared__ int wtot[4];
    const int b   = blockIdx.x;
    const int beg = offs[(size_t)b * nb3];
    const int end = offs[(size_t)(b + 1) * nb3];   // offs[M] = E for last bin
    hist[threadIdx.x] = 0;
    __syncthreads();
    for (int i = beg + threadIdx.x; i < end; i += 256)
        atomicAdd(&hist[tmp[i] >> 17], 1);
    __syncthreads();
    const int lane = threadIdx.x & 63;
    const int wid  = threadIdx.x >> 6;
    int v = hist[threadIdx.x];
    int x = v;
#pragma unroll
    for (int off = 1; off < 64; off <<= 1) {
        int t = __shfl_up(x, off);
        if (lane >= off) x += t;
    }
    if (lane == 63) wtot[wid] = x;
    __syncthreads();
    int wbase = 0;
    for (int w = 0; w < wid; ++w) wbase += wtot[w];
    cur[threadIdx.x] = beg + wbase + x - v;
    int d = b * 256 + threadIdx.x;
    if (d < n) cnt[d] = v;
    __syncthreads();
    for (int i = beg + threadIdx.x; i < end; i += 256) {
        u32 r = tmp[i];
        int pos = atomicAdd(&cur[r >> 17], 1);
        tmp3[pos] = r & 0x1ffffu;   // src
    }
}

__global__ __launch_bounds__(256) void build_ew(const u32* __restrict__ tmp3,
                                                const int* __restrict__ row_ptr,
                                                const float* __restrict__ dinv,
                                                u32* __restrict__ ew, int n) {
    int d = blockIdx.x * 256 + threadIdx.x;
    if (d >= n) return;
    float dd = dinv[d];
    int beg = row_ptr[d], end = row_ptr[d + 1];
    for (int i = beg; i < end; ++i) {
        u32 s = tmp3[i];
        ew[i] = (s << 15) | pack_w(dinv[s] * dd);
    }
}

// ---------------- weights / GEMM ----------------

__global__ void prep_w(const float* __restrict__ W1, const float* __restrict__ W2,
                       u32* __restrict__ W1t, u32* __restrict__ W2t) {
    int idx = blockIdx.x * 256 + threadIdx.x;
    if (idx < 128 * 64) {
        int nr = idx >> 6, kd = idx & 63;
        W1t[idx] = pack_bf16(W1[(2 * kd) * 128 + nr], W1[(2 * kd + 1) * 128 + nr]);
    } else if (idx < 128 * 64 + 64 * 64) {
        int i = idx - 128 * 64;
        int nr = i >> 6, kd = i & 63;
        W2t[i] = pack_bf16(W2[(2 * kd) * 64 + nr], W2[(2 * kd + 1) * 64 + nr]);
    }
}

// C (slab-major, 8-dword slabs, slab stride cslab dwords) = A @ W.
// C-write: cols nt*8+quad*2 -> slab nt, in-slab quad*2.
// ABF: A slab-major too (aslab stride): frag cols ks*16+quad*4 ->
// slab ks*2+(quad>>1), in-slab (quad&1)*4 — contents bit-identical to the
// old row-major fragment.
template <int OUT, bool ABF>
__global__ __launch_bounds__(256) void gemm_mfma(const void* __restrict__ Ap,
                                                 const u32* __restrict__ Wt,
                                                 u32* __restrict__ C, int n,
                                                 size_t aslab, size_t cslab) {
    constexpr int NT = OUT / 16;
    const int lane = threadIdx.x & 63;
    const int wv   = threadIdx.x >> 6;
    const int r15  = lane & 15;
    const int quad = lane >> 4;
    const int rowbase = blockIdx.x * 128 + wv * 32;

    bfrag af[2][4];
#pragma unroll
    for (int mi = 0; mi < 2; ++mi) {
        int row = rowbase + mi * 16 + r15;
        row = (row < n) ? row : (n - 1);
        if constexpr (ABF) {
            const u32* ar = (const u32*)Ap + (size_t)row * 8 + (quad & 1) * 4;
#pragma unroll
            for (int ks = 0; ks < 4; ++ks)
                af[mi][ks] = as_bfrag(*(const uint4*)(ar + (size_t)(ks * 2 + (quad >> 1)) * aslab));
        } else {
            const float* arf = (const float*)Ap + (size_t)row * 128 + quad * 8;
#pragma unroll
            for (int ks = 0; ks < 4; ++ks) {
                float4 v0 = *(const float4*)(arf + ks * 32);
                float4 v1 = *(const float4*)(arf + ks * 32 + 4);
                uint4 p;
                p.x = pack_bf16(v0.x, v0.y);
                p.y = pack_bf16(v0.z, v0.w);
                p.z = pack_bf16(v1.x, v1.y);
                p.w = pack_bf16(v1.z, v1.w);
                af[mi][ks] = as_bfrag(p);
            }
        }
    }

    f4 acc[2][NT];
#pragma unroll
    for (int mi = 0; mi < 2; ++mi)
#pragma unroll
        for (int nt = 0; nt < NT; ++nt) acc[mi][nt] = (f4)0.0f;

#pragma unroll
    for (int nt = 0; nt < NT; ++nt) {
        const u32* wr = Wt + (size_t)(nt * 16 + r15) * 64 + quad * 4;
#pragma unroll
        for (int ks = 0; ks < 4; ++ks) {
            bfrag bf = as_bfrag(*(const uint4*)(wr + ks * 16));
            acc[0][nt] = __builtin_amdgcn_mfma_f32_16x16x32_bf16(bf, af[0][ks], acc[0][nt], 0, 0, 0);
            acc[1][nt] = __builtin_amdgcn_mfma_f32_16x16x32_bf16(bf, af[1][ks], acc[1][nt], 0, 0, 0);
        }
    }

#pragma unroll
    for (int mi = 0; mi < 2; ++mi) {
        int row = rowbase + mi * 16 + r15;
        if (row < n) {
            u32* cp = C + (size_t)row * 8 + quad * 2;
#pragma unroll
            for (int nt = 0; nt < NT; ++nt) {
                uint2 p;
                p.x = pack_bf16(acc[mi][nt][0], acc[mi][nt][1]);
                p.y = pack_bf16(acc[mi][nt][2], acc[mi][nt][3]);
                *(uint2*)(cp + (size_t)nt * cslab) = p;
            }
        }
    }
}

// ---------------- XCD-pinned slice gathers ----------------

// Layer-1: slice = bid&7 (XCD-pinned slab, 3.2MB -> L2-resident). Wave
// handles 4 nodes serially; per node, 8 edge-slots x 8 dwords, 16-edge
// batches (2 load groups in flight), shfl_xor slot-tree reduce, 32B store.
// ew via nontemporal loads (stream, don't evict the slab).
__global__ __launch_bounds__(256) void gather128s(const u32* __restrict__ h,
                                                  const float* __restrict__ dinv,
                                                  const int* __restrict__ row_ptr,
                                                  const u32* __restrict__ ew,
                                                  const float* __restrict__ bias,
                                                  u32* __restrict__ outp, int n) {
    const int lane  = threadIdx.x & 63;
    const int wid   = rfl(threadIdx.x >> 6);
    const int slice = blockIdx.x & 7;
    const int grp   = blockIdx.x >> 3;
    const int es = lane >> 3, dw = lane & 7;
    const size_t SLAB = (size_t)n * 8;
    const u32* hs = h + (size_t)slice * SLAB;
    u32* os = outp + (size_t)slice * SLAB;
    const float2 b = ((const float2*)bias)[slice * 8 + dw];

    const int node0 = (grp * 4 + wid) * 4;
#pragma unroll 1
    for (int ni = 0; ni < 4; ++ni) {
        const int node = node0 + ni;
        if (node >= n) return;
        const int beg = rfl(row_ptr[node]);
        const int end = rfl(row_ptr[node + 1]);
        float acc0 = 0.0f, acc1 = 0.0f;
        for (int j0 = beg; j0 < end; j0 += 16) {
            int jA = j0 + es,     cA = (jA < end) ? jA : end - 1;
            int jB = j0 + 8 + es, cB = (jB < end) ? jB : end - 1;
            u32 eA = __builtin_nontemporal_load(ew + cA);
            u32 eB = __builtin_nontemporal_load(ew + cB);
            u32 vA = hs[(size_t)(eA >> 15) * 8 + dw];
            u32 vB = hs[(size_t)(eB >> 15) * 8 + dw];
            float wA = (jA < end) ? dec_w(eA) : 0.0f;
            float wB = (jB < end) ? dec_w(eB) : 0.0f;
            acc0 = fmaf(wA, bf_lo(vA), acc0); acc1 = fmaf(wA, bf_hi(vA), acc1);
            acc0 = fmaf(wB, bf_lo(vB), acc0); acc1 = fmaf(wB, bf_hi(vB), acc1);
        }
        acc0 += __shfl_xor(acc0, 8);  acc1 += __shfl_xor(acc1, 8);
        acc0 += __shfl_xor(acc0, 16); acc1 += __shfl_xor(acc1, 16);
        acc0 += __shfl_xor(acc0, 32); acc1 += __shfl_xor(acc1, 32);
        if (es == 0) {
            const float dd = dinv[node];
            u32 sv = hs[(size_t)node * 8 + dw];
            acc0 += fmaf(bf_lo(sv) * dd, dd, b.x);
            acc1 += fmaf(bf_hi(sv) * dd, dd, b.y);
            // relu + bf16 pack
            os[(size_t)node * 8 + dw] = pack_bf16(fmaxf(acc0, 0.0f), fmaxf(acc1, 0.0f));
        }
    }
}

// Layer-2: 4 slabs (h2 = 32 dwords); XCD class = bid&7 -> slice = class&3,
// node-half = class>>2 (two XCDs share a slab, split nodes). fp32 out is
// row-major [n][64]: lanes es==0 write float2 at cols slice*16 + dw*2.
__global__ __launch_bounds__(256) void gather64s(const u32* __restrict__ h,
                                                 const float* __restrict__ dinv,
                                                 const int* __restrict__ row_ptr,
                                                 const u32* __restrict__ ew,
                                                 const float* __restrict__ bias,
                                                 float* __restrict__ outp, int n) {
    const int lane  = threadIdx.x & 63;
    const int wid   = rfl(threadIdx.x >> 6);
    const int x8    = blockIdx.x & 7;
    const int slice = x8 & 3;
    const int half  = x8 >> 2;
    const int grp   = blockIdx.x >> 3;
    const int es = lane >> 3, dw = lane & 7;
    const size_t SLAB = (size_t)n * 8;
    const u32* hs = h + (size_t)slice * SLAB;
    const float2 b = ((const float2*)bias)[slice * 8 + dw];

    const int node0 = ((grp * 2 + half) * 4 + wid) * 4;
#pragma unroll 1
    for (int ni = 0; ni < 4; ++ni) {
        const int node = node0 + ni;
        if (node >= n) return;
        const int beg = rfl(row_ptr[node]);
        const int end = rfl(row_ptr[node + 1]);
        float acc0 = 0.0f, acc1 = 0.0f;
        for (int j0 = beg; j0 < end; j0 += 16) {
            int jA = j0 + es,     cA = (jA < end) ? jA : end - 1;
            int jB = j0 + 8 + es, cB = (jB < end) ? jB : end - 1;
            u32 eA = __builtin_nontemporal_load(ew + cA);
            u32 eB = __builtin_nontemporal_load(ew + cB);
            u32 vA = hs[(size_t)(eA >> 15) * 8 + dw];
            u32 vB = hs[(size_t)(eB >> 15) * 8 + dw];
            float wA = (jA < end) ? dec_w(eA) : 0.0f;
            float wB = (jB < end) ? dec_w(eB) : 0.0f;
            acc0 = fmaf(wA, bf_lo(vA), acc0); acc1 = fmaf(wA, bf_hi(vA), acc1);
            acc0 = fmaf(wB, bf_lo(vB), acc0); acc1 = fmaf(wB, bf_hi(vB), acc1);
        }
        acc0 += __shfl_xor(acc0, 8);  acc1 += __shfl_xor(acc1, 8);
        acc0 += __shfl_xor(acc0, 16); acc1 += __shfl_xor(acc1, 16);
        acc0 += __shfl_xor(acc0, 32); acc1 += __shfl_xor(acc1, 32);
        if (es == 0) {
            const float dd = dinv[node];
            u32 sv = hs[(size_t)node * 8 + dw];
            acc0 += fmaf(bf_lo(sv) * dd, dd, b.x);
            acc1 += fmaf(bf_hi(sv) * dd, dd, b.y);
            ((float2*)(outp + (size_t)node * 64 + slice * 16))[dw] = make_float2(acc0, acc1);
        }
    }
}

extern "C" void kernel_launch(void* const* d_in, const int* in_sizes, int n_in,
                              void* d_out, int out_size, void* d_ws, size_t ws_size,
                              hipStream_t stream) {
    const float* x  = (const float*)d_in[0];
    const int*   ei = (const int*)d_in[1];
    const float* W1 = (const float*)d_in[2];
    const float* b1 = (const float*)d_in[3];
    const float* W2 = (const float*)d_in[4];
    const float* b2 = (const float*)d_in[5];
    float*       out = (float*)d_out;

    const int n = in_sizes[0] / 128;   // 100000
    const int E = in_sizes[1] / 2;     // 1600000
    const int* srcv = ei;
    const int* dstv = ei + E;

    const int NP = 102400;
    u32* wsd = (u32*)d_ws;
    float* dinv    = (float*)wsd;                        // NP
    int*   row_ptr = (int*)(wsd + NP);                   // NP
    u32*   ew      = wsd + 2 * (size_t)NP;               // E
    u32*   h1u     = ew + E;                             // n*64 slab-major (gemm1 C / gather128 in)
    u32*   agg1b   = h1u + (size_t)n * 64;               // n*64 slab-major (gather128 out / gemm2 A)
    u32*   W1t     = agg1b + (size_t)n * 64;             // 8192
    u32*   W2t     = W1t + 8192;                         // 4096
    u32*   h2u     = h1u;                                // gemm2 C (n*32, slab-major), reuses h1u

    // CSR scratch — overlaid on h1u (dead until gemm1 writes it):
    int*   cnt  = (int*)h1u;                             // n
    int*   bco  = (int*)(h1u + 131072);                  // M+1
    u32*   tmp2 = h1u + 524288;                          // E
    u32*   tmp3 = tmp2 + (size_t)E;                      // E
    int*   bsum = (int*)(h1u + 4000000);                 // 512
    int*   boff = bsum + 512;                            // 512

    const int NBIN = (n + 255) >> 8;          // 391
    const int NB3  = (E + 2047) / 2048;       // 782
    const int M    = NBIN * NB3;              // 305,762
    const int MB   = (M + 1023) / 1024;       // 299
    const int NB   = (n + 1023) / 1024;       // 98

    // --- CSR build (no global atomics) ---
    count_bins<<<NB3, 256, 0, stream>>>(dstv, bco, E, NBIN, NB3);
    scan_reduce_g<<<MB, 1024, 0, stream>>>(bco, bsum, M);
    scan_partials<<<1, 64, 0, stream>>>(bsum, boff, bco + M, MB);   // bco[M] = E
    scan_apply_g<<<MB, 1024, 0, stream>>>(bco, boff, M);
    scatter_bins<<<NB3, 256, 0, stream>>>(srcv, dstv, bco, tmp2, E, NBIN, NB3);
    bucket_csr<<<NBIN, 256, 0, stream>>>(tmp2, bco, tmp3, cnt, n, NB3);
    scan_reduce_g<<<NB, 1024, 0, stream>>>(cnt, bsum, n);
    scan_partials<<<1, 64, 0, stream>>>(bsum, boff, row_ptr + n, NB);
    scan_apply_cnt<<<NB, 1024, 0, stream>>>(cnt, boff, row_ptr, dinv, n);
    build_ew<<<(n + 255) / 256, 256, 0, stream>>>(tmp3, row_ptr, dinv, ew, n);

    // --- weights to bf16, transposed ---
    prep_w<<<48, 256, 0, stream>>>(W1, W2, W1t, W2t);

    const size_t SLAB = (size_t)n * 8;
    const int gblocks = (n + 127) / 128;  // 782
    // --- layer 1 ---
    gemm_mfma<128, false><<<gblocks, 256, 0, stream>>>(x, W1t, h1u, n, 0, SLAB);
    gather128s<<<((n + 15) / 16) * 8, 256, 0, stream>>>(h1u, dinv, row_ptr, ew, b1, agg1b, n);

    // --- layer 2 ---
    gemm_mfma<64, true><<<gblocks, 256, 0, stream>>>(agg1b, W2t, h2u, n, SLAB, SLAB);
    gather64s<<<((n + 31) / 32) * 8, 256, 0, stream>>>(h2u, dinv, row_ptr, ew, b2, out, n);
}

// Round 6
// 302.004 us; speedup vs baseline: 1.7315x; 1.7315x over previous
//
#include <hip/hip_runtime.h>

// GCN 2-layer. R6: bf16-MFMA GEMMs (no LDS, operand-swap epilogue). R9:
// atomic-free CSR (two-level bucket sort; device fetch-add ~24 Gops/s wall).
// R10: scalar edge fetch in gathers (uniform s_load batches, SALU weight
// decode). R11 (reverted): feature-slab slicing cut FETCH 193->62MB but 8x'd
// per-edge metadata cost (58->211us) — pull-gather kept row-major; the
// 256B-random-row gather at ~3.3-3.8 TB/s miss-path is treated as the wall.
// R12: chain consolidation — cnt-scan block prefix derived from bco
// (edges with dst<1024b == bco[(4b)*nb3], so scan_reduce(n)+partials(n)
// deleted), M-scan partials inlined into apply, prep_w fused into
// count_bins, totals written as constants; gather64 16-edge flight.
// 4B edge payload src(17b)|ws15. Features bf16-pair packed.

typedef unsigned int u32;
using bfrag = __attribute__((ext_vector_type(8))) short;   // 8 bf16 (4 VGPRs)
using f4    = __attribute__((ext_vector_type(4))) float;   // 4 fp32 acc

__device__ inline u32 pack_bf16(float a, float b) {
    u32 ua = __float_as_uint(a);
    u32 ub = __float_as_uint(b);
    ua += 0x7fffu + ((ua >> 16) & 1u);   // RNE
    ub += 0x7fffu + ((ub >> 16) & 1u);
    return (ua >> 16) | (ub & 0xffff0000u);
}
__device__ inline float bf_lo(u32 v) { return __uint_as_float(v << 16); }
__device__ inline float bf_hi(u32 v) { return __uint_as_float(v & 0xffff0000u); }

// w in [2^-8, 1] -> 15 bits: ws = (bits(w) + rnd - 0x3B800000) >> 12.
__device__ inline u32 pack_w(float w) {
    u32 b = __float_as_uint(w) + 0x800u;       // round mantissa at 11 bits
    if (b < 0x3B800000u) b = 0x3B800000u;      // clamp to 2^-8 (unreachable)
    if (b > 0x3F800000u) b = 0x3F800000u;      // clamp to 1.0
    return (b - 0x3B800000u) >> 12;            // 15 bits
}
__device__ inline float dec_w(u32 e) {
    return __uint_as_float(((e & 0x7fffu) << 12) + 0x3B800000u);
}

__device__ inline bfrag as_bfrag(uint4 v) {
    union { uint4 u; bfrag b; } x; x.u = v; return x.b;
}

// ---------------- atomic-free CSR build ----------------

// Per-block LDS histogram over coarse bins (dst>>8) -> bc[bin][block].
// Fused: blocks >= nb3 run the prep_w weight transpose (independent work);
// block 0 also writes the scan total bc[M] = E (constant).
__global__ __launch_bounds__(256) void count_bins_pw(const int* __restrict__ dst,
                                                     int* __restrict__ bc,
                                                     int E, int nbin, int nb3, int M,
                                                     const float* __restrict__ W1,
                                                     const float* __restrict__ W2,
                                                     u32* __restrict__ W1t,
                                                     u32* __restrict__ W2t) {
    __shared__ int hist[512];
    if (blockIdx.x >= (unsigned)nb3) {
        int idx = (blockIdx.x - nb3) * 256 + threadIdx.x;
        if (idx < 128 * 64) {
            int nr = idx >> 6, kd = idx & 63;
            W1t[idx] = pack_bf16(W1[(2 * kd) * 128 + nr], W1[(2 * kd + 1) * 128 + nr]);
        } else if (idx < 128 * 64 + 64 * 64) {
            int i = idx - 128 * 64;
            int nr = i >> 6, kd = i & 63;
            W2t[i] = pack_bf16(W2[(2 * kd) * 64 + nr], W2[(2 * kd + 1) * 64 + nr]);
        }
        return;
    }
    if (blockIdx.x == 0 && threadIdx.x == 0) bc[M] = E;
    for (int t = threadIdx.x; t < nbin; t += 256) hist[t] = 0;
    __syncthreads();
    const int base = blockIdx.x * 2048 + threadIdx.x;
#pragma unroll
    for (int k = 0; k < 8; ++k) {
        int e = base + k * 256;
        if (e < E) atomicAdd(&hist[dst[e] >> 8], 1);
    }
    __syncthreads();
    for (int t = threadIdx.x; t < nbin; t += 256)
        bc[(size_t)t * nb3 + blockIdx.x] = hist[t];
}

// M-scan phase 1: per-1024-chunk sums.
__global__ __launch_bounds__(1024) void scan_reduce_g(const int* __restrict__ a,
                                                      int* __restrict__ bsum, int M) {
    __shared__ int wsum[16];
    int i = blockIdx.x * 1024 + threadIdx.x;
    int v = (i < M) ? a[i] : 0;
#pragma unroll
    for (int off = 32; off > 0; off >>= 1) v += __shfl_down(v, off);
    const int lane = threadIdx.x & 63;
    const int wid  = threadIdx.x >> 6;
    if (lane == 0) wsum[wid] = v;
    __syncthreads();
    if (threadIdx.x < 16) {
        int s = wsum[threadIdx.x];
#pragma unroll
        for (int off = 8; off > 0; off >>= 1) s += __shfl_down(s, off);
        if (threadIdx.x == 0) bsum[blockIdx.x] = s;
    }
}

// M-scan phase 2: in-place exclusive prefix, block prefix computed inline
// from bsum (nb <= 1024 entries; replaces the scan_partials launch).
__global__ __launch_bounds__(1024) void scan_apply_g2(int* __restrict__ a,
                                                      const int* __restrict__ bsum,
                                                      int nb, int M) {
    __shared__ int wsum[16];
    __shared__ int base_s;
    const int lane = threadIdx.x & 63;
    const int wid  = threadIdx.x >> 6;

    // block prefix: sum of bsum[0..blockIdx.x)
    int pv = 0;
    for (int t = threadIdx.x; t < (int)blockIdx.x; t += 1024) pv += bsum[t];
#pragma unroll
    for (int off = 32; off > 0; off >>= 1) pv += __shfl_down(pv, off);
    if (lane == 0) wsum[wid] = pv;
    __syncthreads();
    if (threadIdx.x == 0) {
        int s = 0;
#pragma unroll
        for (int w = 0; w < 16; ++w) s += wsum[w];
        base_s = s;
    }
    __syncthreads();
    const int boff = base_s;

    int i = blockIdx.x * 1024 + threadIdx.x;
    int v = (i < M) ? a[i] : 0;
    int x = v;
#pragma unroll
    for (int off = 1; off < 64; off <<= 1) {
        int t = __shfl_up(x, off);
        if (lane >= off) x += t;
    }
    if (lane == 63) wsum[wid] = x;
    __syncthreads();
    if (wid == 0 && lane < 16) {
        int w = wsum[lane];
#pragma unroll
        for (int off = 1; off < 16; off <<= 1) {
            int t = __shfl_up(w, off);
            if (lane >= off) w += t;
        }
        wsum[lane] = w;
    }
    __syncthreads();
    int wave_excl = (wid == 0) ? 0 : wsum[wid - 1];
    if (i < M) a[i] = boff + wave_excl + (x - v);
}

// cnt-scan (single launch): block prefix is bco[(4*blockIdx.x)*nb3] — the
// number of edges with dst < 1024*blockIdx.x, already computed by the M-scan.
// Writes row_ptr + dinv; row_ptr[n] = E (constant).
__global__ __launch_bounds__(1024) void scan_apply_cnt2(const int* __restrict__ cnt,
                                                        const int* __restrict__ bco,
                                                        int* __restrict__ row_ptr,
                                                        float* __restrict__ dinv,
                                                        int n, int nb3, int E) {
    __shared__ int wsum[16];
    const int lane = threadIdx.x & 63;
    const int wid  = threadIdx.x >> 6;
    const int boff = bco[(size_t)(4 * blockIdx.x) * nb3];
    int i = blockIdx.x * 1024 + threadIdx.x;
    int v = (i < n) ? cnt[i] : 0;
    int x = v;
#pragma unroll
    for (int off = 1; off < 64; off <<= 1) {
        int t = __shfl_up(x, off);
        if (lane >= off) x += t;
    }
    if (lane == 63) wsum[wid] = x;
    __syncthreads();
    if (wid == 0 && lane < 16) {
        int w = wsum[lane];
#pragma unroll
        for (int off = 1; off < 16; off <<= 1) {
            int t = __shfl_up(w, off);
            if (lane >= off) w += t;
        }
        wsum[lane] = w;
    }
    __syncthreads();
    int wave_excl = (wid == 0) ? 0 : wsum[wid - 1];
    if (i < n) {
        row_ptr[i] = boff + wave_excl + (x - v);
        dinv[i]    = rsqrtf((float)v + 1.0f);
    }
    if (blockIdx.x == 0 && threadIdx.x == 0) row_ptr[n] = E;
}

// Scatter edges into per-(bin,block) reserved ranges via LDS cursors.
// Record: (dst&255)<<17 | src  (25 bits).
__global__ __launch_bounds__(256) void scatter_bins(const int* __restrict__ src,
                                                    const int* __restrict__ dst,
                                                    const int* __restrict__ offs,
                                                    u32* __restrict__ tmp,
                                                    int E, int nbin, int nb3) {
    __shared__ int cur[512];
    for (int t = threadIdx.x; t < nbin; t += 256)
        cur[t] = offs[(size_t)t * nb3 + blockIdx.x];
    __syncthreads();
    const int base = blockIdx.x * 2048 + threadIdx.x;
#pragma unroll
    for (int k = 0; k < 8; ++k) {
        int e = base + k * 256;
        if (e < E) {
            int d = dst[e];
            int pos = atomicAdd(&cur[d >> 8], 1);
            tmp[pos] = ((u32)(d & 255) << 17) | (u32)src[e];
        }
    }
}

// One block per bin: LDS 256-bin hist over the bucket (nodes block-exclusive),
// write cnt non-atomically, scatter src into fully-dst-sorted tmp3.
// Sorted position == final CSR position.
__global__ __launch_bounds__(256) void bucket_csr(const u32* __restrict__ tmp,
                                                  const int* __restrict__ offs,
                                                  u32* __restrict__ tmp3,
                                                  int* __restrict__ cnt,
                                                  int n, int nb3) {
    __shared__ int hist[256];
    __shared__ int cur[256];
    __shared__ int wtot[4];
    const int b   = blockIdx.x;
    const int beg = offs[(size_t)b * nb3];
    const int end = offs[(size_t)(b + 1) * nb3];   // offs[M] = E for last bin
    hist[threadIdx.x] = 0;
    __syncthreads();
    for (int i = beg + threadIdx.x; i < end; i += 256)
        atomicAdd(&hist[tmp[i] >> 17], 1);
    __syncthreads();
    const int lane = threadIdx.x & 63;
    const int wid  = threadIdx.x >> 6;
    int v = hist[threadIdx.x];
    int x = v;
#pragma unroll
    for (int off = 1; off < 64; off <<= 1) {
        int t = __shfl_up(x, off);
        if (lane >= off) x += t;
    }
    if (lane == 63) wtot[wid] = x;
    __syncthreads();
    int wbase = 0;
    for (int w = 0; w < wid; ++w) wbase += wtot[w];
    cur[threadIdx.x] = beg + wbase + x - v;
    int d = b * 256 + threadIdx.x;
    if (d < n) cnt[d] = v;
    __syncthreads();
    for (int i = beg + threadIdx.x; i < end; i += 256) {
        u32 r = tmp[i];
        int pos = atomicAdd(&cur[r >> 17], 1);
        tmp3[pos] = r & 0x1ffffu;   // src
    }
}

// Coalesced-ish ew build: thread per node, sequential slots.
__global__ __launch_bounds__(256) void build_ew(const u32* __restrict__ tmp3,
                                                const int* __restrict__ row_ptr,
                                                const float* __restrict__ dinv,
                                                u32* __restrict__ ew, int n) {
    int d = blockIdx.x * 256 + threadIdx.x;
    if (d >= n) return;
    float dd = dinv[d];
    int beg = row_ptr[d], end = row_ptr[d + 1];
    for (int i = beg; i < end; ++i) {
        u32 s = tmp3[i];
        ew[i] = (s << 15) | pack_w(dinv[s] * dd);
    }
}

// ---------------- GEMM ----------------

// C[n][OUT] bf16-packed = A[n][128] @ W[128][OUT], via 16x16x32 bf16 MFMA.
// No LDS. Wave handles 32 rows (2 m-frags). Operand swap: mfma(w_frag, a_frag)
// -> D tile = C^T layout: C-row = lane&15, C-col = nt*16 + quad*4 + reg, so
// each lane holds 4 consecutive C-cols -> one uint2 store per tile.
// ABF: A is bf16-pair packed [n][64] dwords; else fp32 [n][128].
template <int OUT, bool ABF>
__global__ __launch_bounds__(256) void gemm_mfma(const void* __restrict__ Ap,
                                                 const u32* __restrict__ Wt,
                                                 u32* __restrict__ C, int n) {
    constexpr int NT = OUT / 16;
    const int lane = threadIdx.x & 63;
    const int wv   = threadIdx.x >> 6;
    const int r15  = lane & 15;
    const int quad = lane >> 4;
    const int rowbase = blockIdx.x * 128 + wv * 32;

    bfrag af[2][4];
#pragma unroll
    for (int mi = 0; mi < 2; ++mi) {
        int row = rowbase + mi * 16 + r15;
        row = (row < n) ? row : (n - 1);
        if constexpr (ABF) {
            const u32* ar = (const u32*)Ap + (size_t)row * 64 + quad * 4;
#pragma unroll
            for (int ks = 0; ks < 4; ++ks)
                af[mi][ks] = as_bfrag(*(const uint4*)(ar + ks * 16));
        } else {
            const float* arf = (const float*)Ap + (size_t)row * 128 + quad * 8;
#pragma unroll
            for (int ks = 0; ks < 4; ++ks) {
                float4 v0 = *(const float4*)(arf + ks * 32);
                float4 v1 = *(const float4*)(arf + ks * 32 + 4);
                uint4 p;
                p.x = pack_bf16(v0.x, v0.y);
                p.y = pack_bf16(v0.z, v0.w);
                p.z = pack_bf16(v1.x, v1.y);
                p.w = pack_bf16(v1.z, v1.w);
                af[mi][ks] = as_bfrag(p);
            }
        }
    }

    f4 acc[2][NT];
#pragma unroll
    for (int mi = 0; mi < 2; ++mi)
#pragma unroll
        for (int nt = 0; nt < NT; ++nt) acc[mi][nt] = (f4)0.0f;

#pragma unroll
    for (int nt = 0; nt < NT; ++nt) {
        const u32* wr = Wt + (size_t)(nt * 16 + r15) * 64 + quad * 4;
#pragma unroll
        for (int ks = 0; ks < 4; ++ks) {
            bfrag bf = as_bfrag(*(const uint4*)(wr + ks * 16));
            acc[0][nt] = __builtin_amdgcn_mfma_f32_16x16x32_bf16(bf, af[0][ks], acc[0][nt], 0, 0, 0);
            acc[1][nt] = __builtin_amdgcn_mfma_f32_16x16x32_bf16(bf, af[1][ks], acc[1][nt], 0, 0, 0);
        }
    }

#pragma unroll
    for (int mi = 0; mi < 2; ++mi) {
        int row = rowbase + mi * 16 + r15;
        if (row < n) {
            u32* cp = C + (size_t)row * (OUT / 2);
#pragma unroll
            for (int nt = 0; nt < NT; ++nt) {
                uint2 p;
                p.x = pack_bf16(acc[mi][nt][0], acc[mi][nt][1]);
                p.y = pack_bf16(acc[mi][nt][2], acc[mi][nt][3]);
                *(uint2*)(cp + nt * 8 + quad * 2) = p;
            }
        }
    }
}

// ---------------- gathers: scalar edge fetch (R10 structure) ----------------

// Layer-1 gather: one wave per node, F=128, h bf16-pair packed [n][64] dwords.
// Edge metadata via uniform s_load batches; SALU weight decode. 16-edge main
// batches; 8-wide scalar-clamped tail (pads re-load node's own last row w=0).
__global__ __launch_bounds__(256) void gather128(const u32* __restrict__ h,
                                                 const float* __restrict__ dinv,
                                                 const int* __restrict__ row_ptr,
                                                 const u32* __restrict__ ew,
                                                 const float* __restrict__ bias,
                                                 u32* __restrict__ outp, int n) {
    const int lane = threadIdx.x & 63;
    int node = blockIdx.x * 4 + (threadIdx.x >> 6);
    if (node >= n) return;
    node = __builtin_amdgcn_readfirstlane(node);

    const float dd  = dinv[node];
    const int   beg = __builtin_amdgcn_readfirstlane(row_ptr[node]);
    const int   end = __builtin_amdgcn_readfirstlane(row_ptr[node + 1]);

    u32 sv = h[(size_t)node * 64 + lane];
    float2 b = ((const float2*)bias)[lane];
    float acc0 = fmaf(bf_lo(sv) * dd, dd, b.x);
    float acc1 = fmaf(bf_hi(sv) * dd, dd, b.y);

    int j = beg;
    for (; j + 16 <= end; j += 16) {
        u32 ep[16];
#pragma unroll
        for (int k = 0; k < 16; ++k) ep[k] = ew[j + k];        // s_load (merged)
        u32 v[16];
#pragma unroll
        for (int k = 0; k < 16; ++k)
            v[k] = h[((size_t)(ep[k] >> 15) << 6) + lane];     // saddr + lane
#pragma unroll
        for (int k = 0; k < 16; ++k) {
            float wf = dec_w(ep[k]);                           // SALU decode
            acc0 = fmaf(wf, bf_lo(v[k]), acc0);
            acc1 = fmaf(wf, bf_hi(v[k]), acc1);
        }
    }
    for (; j < end; j += 8) {
        const int cnt = end - j;                               // 1..15 (SGPR)
        u32 ep[8];
#pragma unroll
        for (int k = 0; k < 8; ++k) {
            int c = j + k;
            ep[k] = ew[(c < end) ? c : end - 1];               // scalar clamp
        }
        u32 v[8];
#pragma unroll
        for (int k = 0; k < 8; ++k)
            v[k] = h[((size_t)(ep[k] >> 15) << 6) + lane];     // pads: L1-hot row
#pragma unroll
        for (int k = 0; k < 8; ++k) {
            float wf = (k < cnt) ? dec_w(ep[k]) : 0.0f;        // scalar select
            acc0 = fmaf(wf, bf_lo(v[k]), acc0);
            acc1 = fmaf(wf, bf_hi(v[k]), acc1);
        }
    }

    // relu + bf16 pack (relu commutes with RNE quantization)
    outp[(size_t)node * 64 + lane] = pack_bf16(fmaxf(acc0, 0.0f), fmaxf(acc1, 0.0f));
}

// Layer-2 gather: one wave per node, F=64 (32 packed dwords), half-wave per
// edge. Scalar edge fetch; 16-edge main batches (8 pair-steps in flight);
// 8-wide clamped tail. fp32 out.
__global__ __launch_bounds__(256) void gather64(const u32* __restrict__ h,
                                                const float* __restrict__ dinv,
                                                const int* __restrict__ row_ptr,
                                                const u32* __restrict__ ew,
                                                const float* __restrict__ bias,
                                                float* __restrict__ outp, int n) {
    const int lane   = threadIdx.x & 63;
    const int lane32 = lane & 31;
    const int sub    = lane >> 5;
    int node = blockIdx.x * 4 + (threadIdx.x >> 6);
    if (node >= n) return;
    node = __builtin_amdgcn_readfirstlane(node);

    const int beg = __builtin_amdgcn_readfirstlane(row_ptr[node]);
    const int end = __builtin_amdgcn_readfirstlane(row_ptr[node + 1]);

    float acc0 = 0.0f, acc1 = 0.0f;
    if (sub == 0) {
        const float dd = dinv[node];
        u32 sv = h[(size_t)node * 32 + lane32];
        float2 b = ((const float2*)bias)[lane32];
        acc0 = fmaf(bf_lo(sv) * dd, dd, b.x);
        acc1 = fmaf(bf_hi(sv) * dd, dd, b.y);
    }

    int j = beg;
    for (; j + 16 <= end; j += 16) {
        u32 ep[16];
#pragma unroll
        for (int k = 0; k < 16; ++k) ep[k] = ew[j + k];        // s_load (merged)
        u32 v[8]; float wl[8];
#pragma unroll
        for (int p = 0; p < 8; ++p) {
            u32 e0 = ep[2 * p], e1 = ep[2 * p + 1];
            u32 so = sub ? (e1 >> 15) : (e0 >> 15);            // cndmask
            wl[p]  = sub ? dec_w(e1) : dec_w(e0);              // cndmask
            v[p]   = h[((size_t)so << 5) + lane32];
        }
#pragma unroll
        for (int p = 0; p < 8; ++p) {
            acc0 = fmaf(wl[p], bf_lo(v[p]), acc0);
            acc1 = fmaf(wl[p], bf_hi(v[p]), acc1);
        }
    }
    for (; j < end; j += 8) {
        const int cnt = end - j;                               // 1..15 (SGPR)
        u32 ep[8];
#pragma unroll
        for (int k = 0; k < 8; ++k) {
            int c = j + k;
            ep[k] = ew[(c < end) ? c : end - 1];               // scalar clamp
        }
        u32 v[4]; float wl[4];
#pragma unroll
        for (int p = 0; p < 4; ++p) {
            u32 e0 = ep[2 * p], e1 = ep[2 * p + 1];
            float w0 = (2 * p     < cnt) ? dec_w(e0) : 0.0f;   // scalar select
            float w1 = (2 * p + 1 < cnt) ? dec_w(e1) : 0.0f;
            u32 so = sub ? (e1 >> 15) : (e0 >> 15);
            wl[p]  = sub ? w1 : w0;
            v[p]   = h[((size_t)so << 5) + lane32];            // pads: L1-hot row
        }
#pragma unroll
        for (int p = 0; p < 4; ++p) {
            acc0 = fmaf(wl[p], bf_lo(v[p]), acc0);
            acc1 = fmaf(wl[p], bf_hi(v[p]), acc1);
        }
    }

    acc0 += __shfl_xor(acc0, 32);
    acc1 += __shfl_xor(acc1, 32);
    if (sub == 0)
        ((float2*)(outp + (size_t)node * 64))[lane32] = make_float2(acc0, acc1);
}

extern "C" void kernel_launch(void* const* d_in, const int* in_sizes, int n_in,
                              void* d_out, int out_size, void* d_ws, size_t ws_size,
                              hipStream_t stream) {
    const float* x  = (const float*)d_in[0];
    const int*   ei = (const int*)d_in[1];
    const float* W1 = (const float*)d_in[2];
    const float* b1 = (const float*)d_in[3];
    const float* W2 = (const float*)d_in[4];
    const float* b2 = (const float*)d_in[5];
    float*       out = (float*)d_out;

    const int n = in_sizes[0] / 128;   // 100000
    const int E = in_sizes[1] / 2;     // 1600000
    const int* srcv = ei;
    const int* dstv = ei + E;

    const int NP = 102400;
    u32* wsd = (u32*)d_ws;
    float* dinv    = (float*)wsd;                        // NP
    int*   row_ptr = (int*)(wsd + NP);                   // NP
    u32*   ew      = wsd + 2 * (size_t)NP;               // E
    u32*   h1u     = ew + E;                             // n*64 (gemm1 C / gather128 in)
    u32*   agg1b   = h1u + (size_t)n * 64;               // n*64 (gather128 out / gemm2 A)
    u32*   W1t     = agg1b + (size_t)n * 64;             // 8192
    u32*   W2t     = W1t + 8192;                         // 4096
    u32*   h2u     = h1u;                                // gemm2 C: n*32, reuses h1u

    // CSR scratch — overlaid on h1u (dead until gemm1 writes it):
    int*   cnt  = (int*)h1u;                             // n
    int*   bco  = (int*)(h1u + 131072);                  // M+1
    u32*   tmp2 = h1u + 524288;                          // E
    u32*   tmp3 = tmp2 + (size_t)E;                      // E
    int*   bsum = (int*)(h1u + 4000000);                 // 512

    const int NBIN = (n + 255) >> 8;          // 391
    const int NB3  = (E + 2047) / 2048;       // 782
    const int M    = NBIN * NB3;              // 305,762
    const int MB   = (M + 1023) / 1024;       // 299
    const int NB   = (n + 1023) / 1024;       // 98

    // --- CSR build (no global atomics; 7 launches) ---
    count_bins_pw<<<NB3 + 48, 256, 0, stream>>>(dstv, bco, E, NBIN, NB3, M,
                                                W1, W2, W1t, W2t);
    scan_reduce_g<<<MB, 1024, 0, stream>>>(bco, bsum, M);
    scan_apply_g2<<<MB, 1024, 0, stream>>>(bco, bsum, MB, M);
    scatter_bins<<<NB3, 256, 0, stream>>>(srcv, dstv, bco, tmp2, E, NBIN, NB3);
    bucket_csr<<<NBIN, 256, 0, stream>>>(tmp2, bco, tmp3, cnt, n, NB3);
    scan_apply_cnt2<<<NB, 1024, 0, stream>>>(cnt, bco, row_ptr, dinv, n, NB3, E);
    build_ew<<<(n + 255) / 256, 256, 0, stream>>>(tmp3, row_ptr, dinv, ew, n);

    const int gblocks = (n + 127) / 128;  // 782
    // --- layer 1 ---
    gemm_mfma<128, false><<<gblocks, 256, 0, stream>>>(x, W1t, h1u, n);
    gather128<<<(n + 3) / 4, 256, 0, stream>>>(h1u, dinv, row_ptr, ew, b1, agg1b, n);

    // --- layer 2 ---
    gemm_mfma<64, true><<<gblocks, 256, 0, stream>>>(agg1b, W2t, h2u, n);
    gather64<<<(n + 3) / 4, 256, 0, stream>>>(h2u, dinv, row_ptr, ew, b2, out, n);
}